// Round 3
// baseline (148.146 us; speedup 1.0000x reference)
//
#include <hip/hip_runtime.h>

#define N 4096
#define K 8
#define BI 16           // rows of A per block in the pair kernel
#define NPB 16          // prep blocks (N/256)

__device__ __forceinline__ float fast_exp2(float x) { return __builtin_amdgcn_exp2f(x); }
__device__ __forceinline__ float fast_log2(float x) { return __builtin_amdgcn_logf(x); }
__device__ __forceinline__ float fast_sqrt(float x) { return __builtin_amdgcn_sqrtf(x); }

// ---------------------------------------------------------------------------
// Pass 1: ZsT[n][k] = softmax_k(Z[:,n]); per-block partial
// Upart[blk][a*8+b] = sum_{n in blk} ZsT[n][a]*exp(C[n][b]).
// No global atomics, no memset needed. Note S[b] = sum_a U[a][b] since
// sum_a ZsT[n][a] = 1, so no separate S reduction exists at all.
// Block 0 also zeroes `out` (poisoned 0xAA by the harness each call).
// ---------------------------------------------------------------------------
__global__ __launch_bounds__(256) void prep_stats(
    const float* __restrict__ Z, const float* __restrict__ C,
    float* __restrict__ ZsT, float* __restrict__ Upart, float* __restrict__ out)
{
    const int t = threadIdx.x;
    const int n = blockIdx.x * 256 + t;
    const float L2E = 1.44269504f;

    __shared__ float zsL[256 * K];
    __shared__ float eL[256 * K];
    __shared__ float red[4][64];

    if (blockIdx.x == 0 && t == 0) out[0] = 0.f;

    float z[K];
#pragma unroll
    for (int k = 0; k < K; ++k) z[k] = Z[k * N + n];   // coalesced column reads
    float zmax = z[0];
#pragma unroll
    for (int k = 1; k < K; ++k) zmax = fmaxf(zmax, z[k]);
    float zs[K];
    float zsum = 0.f;
#pragma unroll
    for (int k = 0; k < K; ++k) { zs[k] = fast_exp2((z[k] - zmax) * L2E); zsum += zs[k]; }
    const float inv = 1.f / zsum;
#pragma unroll
    for (int k = 0; k < K; ++k) zs[k] *= inv;

    float4* zst_p = (float4*)(ZsT + (size_t)n * K);
    zst_p[0] = make_float4(zs[0], zs[1], zs[2], zs[3]);
    zst_p[1] = make_float4(zs[4], zs[5], zs[6], zs[7]);

    const float4* c_p = (const float4*)(C + (size_t)n * K);
    const float4 c0 = c_p[0], c1 = c_p[1];
    float e[K];
    e[0] = fast_exp2(c0.x * L2E); e[1] = fast_exp2(c0.y * L2E);
    e[2] = fast_exp2(c0.z * L2E); e[3] = fast_exp2(c0.w * L2E);
    e[4] = fast_exp2(c1.x * L2E); e[5] = fast_exp2(c1.y * L2E);
    e[6] = fast_exp2(c1.z * L2E); e[7] = fast_exp2(c1.w * L2E);

#pragma unroll
    for (int k = 0; k < K; ++k) { zsL[t * K + k] = zs[k]; eL[t * K + k] = e[k]; }
    __syncthreads();

    // all 256 threads active: thread owns cell (a,b), quarter q of the nodes
    const int cell = t & 63, q = t >> 6;
    const int a = cell >> 3, b = cell & 7;
    float s = 0.f;
    const int n0 = q * 64;
#pragma unroll 4
    for (int nn = 0; nn < 64; ++nn)
        s = fmaf(zsL[(n0 + nn) * K + a], eL[(n0 + nn) * K + b], s);
    red[q][cell] = s;
    __syncthreads();
    if (t < 64)
        Upart[blockIdx.x * 64 + t] = red[0][t] + red[1][t] + red[2][t] + red[3][t];
}

// ---------------------------------------------------------------------------
// Pass 2: fold Upart -> U, S; M[n][k] = sum_k' (U[k][k']/S[k']) * ZsT[n][k'].
// Also subtracts the exact diagonal contribution from `out`:
//   theta_ii = 2*beta_i - a*sqrt(8)*1e-6;  diag = theta_ii*A_ii - softplus(theta_ii)
// ---------------------------------------------------------------------------
__global__ __launch_bounds__(256) void prep_M(
    const float* __restrict__ ZsT, const float* __restrict__ Upart,
    const float* __restrict__ A, const float* __restrict__ beta,
    const float* __restrict__ a_ptr, float* __restrict__ M, float* __restrict__ out)
{
    const int t = threadIdx.x;
    const int n = blockIdx.x * 256 + t;
    const float L2E = 1.44269504f;
    const float LN2 = 0.69314718f;

    __shared__ float UL[64];
    __shared__ float SinvL[8];
    if (t < 64) {
        float s = 0.f;
#pragma unroll
        for (int blk = 0; blk < NPB; ++blk) s += Upart[blk * 64 + t];
        UL[t] = s;
    }
    __syncthreads();
    if (t < 8) {
        float s = 0.f;
#pragma unroll
        for (int a = 0; a < 8; ++a) s += UL[a * 8 + t];   // S[b] = sum_a U[a][b]
        SinvL[t] = 1.f / s;
    }
    __syncthreads();

    const float4* zst_p = (const float4*)(ZsT + (size_t)n * K);
    const float4 z0 = zst_p[0], z1 = zst_p[1];
    float w[K];
    w[0] = z0.x * SinvL[0]; w[1] = z0.y * SinvL[1]; w[2] = z0.z * SinvL[2]; w[3] = z0.w * SinvL[3];
    w[4] = z1.x * SinvL[4]; w[5] = z1.y * SinvL[5]; w[6] = z1.z * SinvL[6]; w[7] = z1.w * SinvL[7];
    float m[K];
#pragma unroll
    for (int k = 0; k < K; ++k) {
        float acc = 0.f;
#pragma unroll
        for (int kk = 0; kk < K; ++kk) acc = fmaf(UL[k * K + kk], w[kk], acc);
        m[k] = acc;
    }
    float4* m_p = (float4*)(M + (size_t)n * K);
    m_p[0] = make_float4(m[0], m[1], m[2], m[3]);
    m_p[1] = make_float4(m[4], m[5], m[6], m[7]);

    // exact diagonal contribution (subtracted from out)
    const float av = A[(size_t)n * N + n];
    const float theta = fmaf(-a_ptr[0], 2.8284271247e-6f, 2.f * beta[n]);
    const float ex = fast_exp2(theta * L2E);
    const float sp = LN2 * fast_log2(1.f + ex);
    float d = fmaf(theta, av, -sp);

    for (int off = 32; off > 0; off >>= 1) d += __shfl_down(d, off, 64);
    __shared__ float wsum[4];
    const int lane = t & 63, wid = t >> 6;
    if (lane == 0) wsum[wid] = d;
    __syncthreads();
    if (t == 0) atomicAdd(out, -(wsum[0] + wsum[1] + wsum[2] + wsum[3]));
}

// ---------------------------------------------------------------------------
// Pass 3: LL += sum_{all i,j} theta_ij*A_ij - softplus(theta_ij)
// theta = beta_i + beta_j - a*sqrt(|Mi'|^2 + |Mj|^2 - 2 Mi'.Mj), Mi' = M[i]+1e-6.
// One column j per thread (coalesced dword A loads), BI=16 rows per block.
// Per-thread state is small (~50 VGPR) so everything stays register-resident;
// all 16 A loads are independent and issue up front.
// Log2-domain: t2 = theta*log2(e); softplus = ln2*log2(1+2^t2); scale once.
// ---------------------------------------------------------------------------
__global__ __launch_bounds__(256) void pair_ll(
    const float* __restrict__ A, const float* __restrict__ beta,
    const float* __restrict__ a_ptr, const float* __restrict__ M,
    float* __restrict__ out)
{
    const int t = threadIdx.x;
    const int i0 = blockIdx.x * BI;
    const int j = blockIdx.y * 256 + t;
    const float L2E = 1.44269504f;
    const float LN2 = 0.69314718f;

    __shared__ __align__(16) float4 ntwoMi[BI][2];   // -2*(M[i]+1e-6)
    __shared__ __align__(8)  float2 rc[BI];          // {|Mi'|^2, beta_i*L2E}
    if (t < BI) {
        const float4* mp = (const float4*)(M + (size_t)(i0 + t) * K);
        const float4 a0 = mp[0], a1 = mp[1];
        float v[K] = { a0.x + 1e-6f, a0.y + 1e-6f, a0.z + 1e-6f, a0.w + 1e-6f,
                       a1.x + 1e-6f, a1.y + 1e-6f, a1.z + 1e-6f, a1.w + 1e-6f };
        float s2 = 0.f;
#pragma unroll
        for (int k = 0; k < K; ++k) s2 = fmaf(v[k], v[k], s2);
        ntwoMi[t][0] = make_float4(-2.f * v[0], -2.f * v[1], -2.f * v[2], -2.f * v[3]);
        ntwoMi[t][1] = make_float4(-2.f * v[4], -2.f * v[5], -2.f * v[6], -2.f * v[7]);
        rc[t] = make_float2(s2, beta[i0 + t] * L2E);
    }
    __syncthreads();

    // this thread's column state (register resident)
    const float4* mp = (const float4*)(M + (size_t)j * K);
    const float4 mj0 = mp[0], mj1 = mp[1];
    float mj2 = mj0.x * mj0.x;
    mj2 = fmaf(mj0.y, mj0.y, mj2); mj2 = fmaf(mj0.z, mj0.z, mj2);
    mj2 = fmaf(mj0.w, mj0.w, mj2); mj2 = fmaf(mj1.x, mj1.x, mj2);
    mj2 = fmaf(mj1.y, mj1.y, mj2); mj2 = fmaf(mj1.z, mj1.z, mj2);
    mj2 = fmaf(mj1.w, mj1.w, mj2);
    const float bjL2E = beta[j] * L2E;
    const float naL2E = -a_ptr[0] * L2E;

    // prefetch the whole A column strip (independent loads, SGPR row bases)
    float av[BI];
#pragma unroll
    for (int ii = 0; ii < BI; ++ii)
        av[ii] = A[(size_t)(i0 + ii) * N + j];

    float acc_t = 0.f, acc_l = 0.f;
#pragma unroll
    for (int ii = 0; ii < BI; ++ii) {
        const float4 tm0 = ntwoMi[ii][0];   // LDS b128 broadcast
        const float4 tm1 = ntwoMi[ii][1];
        const float2 c = rc[ii];
        float ss = c.x + mj2;
        ss = fmaf(tm0.x, mj0.x, ss); ss = fmaf(tm0.y, mj0.y, ss);
        ss = fmaf(tm0.z, mj0.z, ss); ss = fmaf(tm0.w, mj0.w, ss);
        ss = fmaf(tm1.x, mj1.x, ss); ss = fmaf(tm1.y, mj1.y, ss);
        ss = fmaf(tm1.z, mj1.z, ss); ss = fmaf(tm1.w, mj1.w, ss);
        ss = fmaxf(ss, 0.f);                        // cancellation guard
        const float dist = fast_sqrt(ss);
        const float t2 = fmaf(naL2E, dist, c.y + bjL2E);  // theta*log2(e)
        const float ex = fast_exp2(t2);                   // = exp(theta), safe
        const float lp = fast_log2(1.f + ex);             // softplus/ln2
        acc_t = fmaf(t2, av[ii], acc_t);
        acc_l += lp;
    }
    float acc = LN2 * (acc_t - acc_l);

    for (int off = 32; off > 0; off >>= 1) acc += __shfl_down(acc, off, 64);
    __shared__ float wsum[4];
    const int lane = t & 63, wid = t >> 6;
    if (lane == 0) wsum[wid] = acc;
    __syncthreads();
    if (t == 0) atomicAdd(out, wsum[0] + wsum[1] + wsum[2] + wsum[3]);
}

extern "C" void kernel_launch(void* const* d_in, const int* in_sizes, int n_in,
                              void* d_out, int out_size, void* d_ws, size_t ws_size,
                              hipStream_t stream)
{
    const float* A    = (const float*)d_in[0];   // [N,N]
    const float* beta = (const float*)d_in[1];   // [N]
    const float* a    = (const float*)d_in[2];   // [1]
    const float* Z    = (const float*)d_in[3];   // [K,N]
    const float* C    = (const float*)d_in[4];   // [N,K]
    float* out = (float*)d_out;

    float* ws    = (float*)d_ws;
    float* ZsT   = ws;                      // N*K floats
    float* M     = ws + (size_t)N * K;      // N*K floats
    float* Upart = ws + (size_t)2 * N * K;  // NPB*64 floats

    prep_stats<<<NPB, 256, 0, stream>>>(Z, C, ZsT, Upart, out);
    prep_M<<<NPB, 256, 0, stream>>>(ZsT, Upart, A, beta, a, M, out);

    dim3 grid(N / BI, N / 256);
    pair_ll<<<grid, 256, 0, stream>>>(A, beta, a, M, out);
}

// Round 4
// 114.400 us; speedup vs baseline: 1.2950x; 1.2950x over previous
//
#include <hip/hip_runtime.h>

#define N 4096
#define K 8
#define RB 64           // rows of A per block (pair kernel)
#define CB 256          // columns of A per block (one per thread)
#define RCH 16          // rows per chunk (LDS staging granularity)
#define NCH (RB / RCH)  // chunks per block
#define NPB 16          // prep blocks (N/256)

__device__ __forceinline__ float fast_exp2(float x) { return __builtin_amdgcn_exp2f(x); }
__device__ __forceinline__ float fast_log2(float x) { return __builtin_amdgcn_logf(x); }
__device__ __forceinline__ float fast_sqrt(float x) { return __builtin_amdgcn_sqrtf(x); }

// Async global->LDS, 16B per lane. LDS dest is wave-uniform base; lane i
// lands at base + i*16 (m97/m104 semantics). One call = one 256-float row.
__device__ __forceinline__ void load_lds_16B(const float* g, float* l) {
    __builtin_amdgcn_global_load_lds((const __attribute__((address_space(1))) void*)g,
                                     (__attribute__((address_space(3))) void*)l,
                                     16, 0, 0);
}

// ---------------------------------------------------------------------------
// Pass 1: ZsT[n][k] = softmax_k(Z[:,n]); per-block partial
// Upart[blk][a*8+b] = sum_{n in blk} ZsT[n][a]*exp(C[n][b]).
// S[b] = sum_a U[a][b] (since softmax rows sum to 1), so S needs no reduction.
// Block 0 zeroes `out` (harness poisons it each call).
// ---------------------------------------------------------------------------
__global__ __launch_bounds__(256) void prep_stats(
    const float* __restrict__ Z, const float* __restrict__ C,
    float* __restrict__ ZsT, float* __restrict__ Upart, float* __restrict__ out)
{
    const int t = threadIdx.x;
    const int n = blockIdx.x * 256 + t;
    const float L2E = 1.44269504f;

    __shared__ float zsL[256 * K];
    __shared__ float eL[256 * K];
    __shared__ float red[4][64];

    if (blockIdx.x == 0 && t == 0) out[0] = 0.f;

    float z[K];
#pragma unroll
    for (int k = 0; k < K; ++k) z[k] = Z[k * N + n];   // coalesced column reads
    float zmax = z[0];
#pragma unroll
    for (int k = 1; k < K; ++k) zmax = fmaxf(zmax, z[k]);
    float zs[K];
    float zsum = 0.f;
#pragma unroll
    for (int k = 0; k < K; ++k) { zs[k] = fast_exp2((z[k] - zmax) * L2E); zsum += zs[k]; }
    const float inv = 1.f / zsum;
#pragma unroll
    for (int k = 0; k < K; ++k) zs[k] *= inv;

    float4* zst_p = (float4*)(ZsT + (size_t)n * K);
    zst_p[0] = make_float4(zs[0], zs[1], zs[2], zs[3]);
    zst_p[1] = make_float4(zs[4], zs[5], zs[6], zs[7]);

    const float4* c_p = (const float4*)(C + (size_t)n * K);
    const float4 c0 = c_p[0], c1 = c_p[1];
    float e[K];
    e[0] = fast_exp2(c0.x * L2E); e[1] = fast_exp2(c0.y * L2E);
    e[2] = fast_exp2(c0.z * L2E); e[3] = fast_exp2(c0.w * L2E);
    e[4] = fast_exp2(c1.x * L2E); e[5] = fast_exp2(c1.y * L2E);
    e[6] = fast_exp2(c1.z * L2E); e[7] = fast_exp2(c1.w * L2E);

#pragma unroll
    for (int k = 0; k < K; ++k) { zsL[t * K + k] = zs[k]; eL[t * K + k] = e[k]; }
    __syncthreads();

    const int cell = t & 63, q = t >> 6;
    const int a = cell >> 3, b = cell & 7;
    float s = 0.f;
    const int n0 = q * 64;
#pragma unroll 4
    for (int nn = 0; nn < 64; ++nn)
        s = fmaf(zsL[(n0 + nn) * K + a], eL[(n0 + nn) * K + b], s);
    red[q][cell] = s;
    __syncthreads();
    if (t < 64)
        Upart[blockIdx.x * 64 + t] = red[0][t] + red[1][t] + red[2][t] + red[3][t];
}

// ---------------------------------------------------------------------------
// Pass 2: fold Upart -> U, S; M[n][k] = sum_k' (U[k][k']/S[k']) * ZsT[n][k'].
// Also subtracts the exact diagonal contribution from `out`:
//   theta_ii = 2*beta_i - a*sqrt(8)*1e-6;  diag = theta_ii*A_ii - softplus(theta_ii)
// ---------------------------------------------------------------------------
__global__ __launch_bounds__(256) void prep_M(
    const float* __restrict__ ZsT, const float* __restrict__ Upart,
    const float* __restrict__ A, const float* __restrict__ beta,
    const float* __restrict__ a_ptr, float* __restrict__ M, float* __restrict__ out)
{
    const int t = threadIdx.x;
    const int n = blockIdx.x * 256 + t;
    const float L2E = 1.44269504f;
    const float LN2 = 0.69314718f;

    __shared__ float UL[64];
    __shared__ float SinvL[8];
    if (t < 64) {
        float s = 0.f;
#pragma unroll
        for (int blk = 0; blk < NPB; ++blk) s += Upart[blk * 64 + t];
        UL[t] = s;
    }
    __syncthreads();
    if (t < 8) {
        float s = 0.f;
#pragma unroll
        for (int a = 0; a < 8; ++a) s += UL[a * 8 + t];   // S[b] = sum_a U[a][b]
        SinvL[t] = 1.f / s;
    }
    __syncthreads();

    const float4* zst_p = (const float4*)(ZsT + (size_t)n * K);
    const float4 z0 = zst_p[0], z1 = zst_p[1];
    float w[K];
    w[0] = z0.x * SinvL[0]; w[1] = z0.y * SinvL[1]; w[2] = z0.z * SinvL[2]; w[3] = z0.w * SinvL[3];
    w[4] = z1.x * SinvL[4]; w[5] = z1.y * SinvL[5]; w[6] = z1.z * SinvL[6]; w[7] = z1.w * SinvL[7];
    float m[K];
#pragma unroll
    for (int k = 0; k < K; ++k) {
        float acc = 0.f;
#pragma unroll
        for (int kk = 0; kk < K; ++kk) acc = fmaf(UL[k * K + kk], w[kk], acc);
        m[k] = acc;
    }
    float4* m_p = (float4*)(M + (size_t)n * K);
    m_p[0] = make_float4(m[0], m[1], m[2], m[3]);
    m_p[1] = make_float4(m[4], m[5], m[6], m[7]);

    const float av = A[(size_t)n * N + n];
    const float theta = fmaf(-a_ptr[0], 2.8284271247e-6f, 2.f * beta[n]);
    const float ex = fast_exp2(theta * L2E);
    const float sp = LN2 * fast_log2(1.f + ex);
    float d = fmaf(theta, av, -sp);

    for (int off = 32; off > 0; off >>= 1) d += __shfl_down(d, off, 64);
    __shared__ float wsum[4];
    const int lane = t & 63, wid = t >> 6;
    if (lane == 0) wsum[wid] = d;
    __syncthreads();
    if (t == 0) atomicAdd(out, -(wsum[0] + wsum[1] + wsum[2] + wsum[3]));
}

// ---------------------------------------------------------------------------
// Pass 3: LL += sum_{all i,j} theta_ij*A_ij - softplus(theta_ij)
// theta = beta_i + beta_j - a*sqrt(|Mi'|^2 + |Mj|^2 - 2 Mi'.Mj), Mi' = M[i]+1e-6.
// A staged via async global_load_lds (16B/lane; 1 wave-call = 1 row segment),
// double-buffered: chunk c+1 loads fly while chunk c computes; the pre-barrier
// vmcnt(0) drain lands AFTER the compute. No VGPRs consumed by loads, so the
// register-minimizing scheduler can't serialize them (the R2/R3 failure).
// Thread owns a fixed column j; Mi constants for the 64-row panel sit in LDS.
// ---------------------------------------------------------------------------
__global__ __launch_bounds__(256) void pair_ll(
    const float* __restrict__ A, const float* __restrict__ beta,
    const float* __restrict__ a_ptr, const float* __restrict__ M,
    float* __restrict__ out)
{
    const int t = threadIdx.x;
    const int lane = t & 63, w = t >> 6;
    const int i0 = blockIdx.x * RB;
    const int jbase = blockIdx.y * CB;
    const int j = jbase + t;
    const float L2E = 1.44269504f;
    const float LN2 = 0.69314718f;

    __shared__ __align__(16) float Abuf[2][RCH][CB];   // 32 KB
    __shared__ __align__(16) float4 ntwoMi[RB][2];     // -2*(M[i]+1e-6)
    __shared__ __align__(8)  float2 rc[RB];            // {|Mi'|^2, beta_i*L2E}
    __shared__ float wsum[4];

    // stage per-row constants for the whole 64-row panel
    if (t < RB) {
        const float4* mp = (const float4*)(M + (size_t)(i0 + t) * K);
        const float4 a0 = mp[0], a1 = mp[1];
        float v[K] = { a0.x + 1e-6f, a0.y + 1e-6f, a0.z + 1e-6f, a0.w + 1e-6f,
                       a1.x + 1e-6f, a1.y + 1e-6f, a1.z + 1e-6f, a1.w + 1e-6f };
        float s2 = 0.f;
#pragma unroll
        for (int k = 0; k < K; ++k) s2 = fmaf(v[k], v[k], s2);
        ntwoMi[t][0] = make_float4(-2.f * v[0], -2.f * v[1], -2.f * v[2], -2.f * v[3]);
        ntwoMi[t][1] = make_float4(-2.f * v[4], -2.f * v[5], -2.f * v[6], -2.f * v[7]);
        rc[t] = make_float2(s2, beta[i0 + t] * L2E);
    }

    // per-thread column state (fixed for the whole block)
    const float4* mp = (const float4*)(M + (size_t)j * K);
    const float4 mj0 = mp[0], mj1 = mp[1];
    float mj2 = mj0.x * mj0.x;
    mj2 = fmaf(mj0.y, mj0.y, mj2); mj2 = fmaf(mj0.z, mj0.z, mj2);
    mj2 = fmaf(mj0.w, mj0.w, mj2); mj2 = fmaf(mj1.x, mj1.x, mj2);
    mj2 = fmaf(mj1.y, mj1.y, mj2); mj2 = fmaf(mj1.z, mj1.z, mj2);
    mj2 = fmaf(mj1.w, mj1.w, mj2);
    const float bjL2E = beta[j] * L2E;
    const float naL2E = -a_ptr[0] * L2E;

    // issue chunk 0 (wave w stages rows w*4 .. w*4+3 of the chunk)
    {
        const float* g = A + (size_t)(i0 + w * 4) * N + jbase + lane * 4;
#pragma unroll
        for (int rr = 0; rr < 4; ++rr)
            load_lds_16B(g + (size_t)rr * N, &Abuf[0][w * 4 + rr][0]);
    }

    float acc_t = 0.f, acc_l = 0.f;
    int buf = 0;
    for (int c = 0; c < NCH; ++c) {
        __syncthreads();   // drains chunk c's loads (vmcnt(0) before s_barrier)
        if (c + 1 < NCH) {
            const float* g = A + (size_t)(i0 + (c + 1) * RCH + w * 4) * N + jbase + lane * 4;
#pragma unroll
            for (int rr = 0; rr < 4; ++rr)
                load_lds_16B(g + (size_t)rr * N, &Abuf[buf ^ 1][w * 4 + rr][0]);
        }
#pragma unroll
        for (int r = 0; r < RCH; ++r) {
            const int ir = c * RCH + r;
            const float av = Abuf[buf][r][t];       // stride-1 LDS, conflict-free
            const float4 tm0 = ntwoMi[ir][0];       // b128 broadcast
            const float4 tm1 = ntwoMi[ir][1];
            const float2 cc = rc[ir];
            float ss = cc.x + mj2;
            ss = fmaf(tm0.x, mj0.x, ss); ss = fmaf(tm0.y, mj0.y, ss);
            ss = fmaf(tm0.z, mj0.z, ss); ss = fmaf(tm0.w, mj0.w, ss);
            ss = fmaf(tm1.x, mj1.x, ss); ss = fmaf(tm1.y, mj1.y, ss);
            ss = fmaf(tm1.z, mj1.z, ss); ss = fmaf(tm1.w, mj1.w, ss);
            ss = fmaxf(ss, 0.f);                    // cancellation guard
            const float dist = fast_sqrt(ss);
            const float t2 = fmaf(naL2E, dist, cc.y + bjL2E);  // theta*log2(e)
            const float ex = fast_exp2(t2);                    // exp(theta), safe
            const float lp = fast_log2(1.f + ex);              // softplus/ln2
            acc_t = fmaf(t2, av, acc_t);
            acc_l += lp;
        }
        buf ^= 1;
    }
    float acc = LN2 * (acc_t - acc_l);

    for (int off = 32; off > 0; off >>= 1) acc += __shfl_down(acc, off, 64);
    if (lane == 0) wsum[w] = acc;
    __syncthreads();
    if (t == 0) atomicAdd(out, wsum[0] + wsum[1] + wsum[2] + wsum[3]);
}

extern "C" void kernel_launch(void* const* d_in, const int* in_sizes, int n_in,
                              void* d_out, int out_size, void* d_ws, size_t ws_size,
                              hipStream_t stream)
{
    const float* A    = (const float*)d_in[0];   // [N,N]
    const float* beta = (const float*)d_in[1];   // [N]
    const float* a    = (const float*)d_in[2];   // [1]
    const float* Z    = (const float*)d_in[3];   // [K,N]
    const float* C    = (const float*)d_in[4];   // [N,K]
    float* out = (float*)d_out;

    float* ws    = (float*)d_ws;
    float* ZsT   = ws;                      // N*K floats
    float* M     = ws + (size_t)N * K;      // N*K floats
    float* Upart = ws + (size_t)2 * N * K;  // NPB*64 floats

    prep_stats<<<NPB, 256, 0, stream>>>(Z, C, ZsT, Upart, out);
    prep_M<<<NPB, 256, 0, stream>>>(ZsT, Upart, A, beta, a, M, out);

    dim3 grid(N / RB, N / CB);
    pair_ll<<<grid, 256, 0, stream>>>(A, beta, a, M, out);
}